// Round 13
// baseline (100.172 us; speedup 1.0000x reference)
//
#include <hip/hip_runtime.h>
#include <hip/hip_fp16.h>
#include <math.h>

#define B_ROWS 131072
#define DDIM 256
#define EPSF 1e-7f
#define NB1 2048            // k_main blocks; 512 thr, 8 waves; 8 rows/wave (2 chains/lane)
#define NWAVES (NB1 * 8)    // 16384 per-wave partial slots
#define NB3 512             // k_rloss blocks; NB3*256 == B_ROWS

// ---------- ws layout (bytes) ----------
#define PBW_OFF  0          // float[NWAVES][9] = 589824
#define RV_OFF   589824     // double[8]
#define PL_OFF   589888     // double[1]
#define PBRL_OFF 589952     // double[NB3] = 4096
#define HW_OFF   594048     // __half[B_ROWS][8] = 2 MB (end ~2.69 MB)

__device__ __forceinline__ float uni(float x) {   // wave-uniform -> SGPR
    return __int_as_float(__builtin_amdgcn_readfirstlane(__float_as_int(x)));
}

// DPP-based add: v += v permuted by ctrl (within 16-lane DPP rows). VALU-only.
#define DPP_ADD(v, ctrl)                                                        \
    (v) += __int_as_float(__builtin_amdgcn_update_dpp(                          \
               0, __float_as_int(v), (ctrl), 0xF, 0xF, true))

// 16-lane all-reduce sum: xor1, xor2 via quad_perm; then row_ror:4, row_ror:8.
#define REDUCE16(v)                                                             \
    do {                                                                        \
        DPP_ADD(v, 0xB1);   /* quad_perm [1,0,3,2]  */                          \
        DPP_ADD(v, 0x4E);   /* quad_perm [2,3,0,1]  */                          \
        DPP_ADD(v, 0x124);  /* row_ror:4            */                          \
        DPP_ADD(v, 0x128);  /* row_ror:8            */                          \
    } while (0)

// ---------------- k1: fused params + main chain (2 independent chains/lane) ----------------
// 512 threads = 8 waves; lane owns 16 elems of rowA and rowB=rowA+4 (8 rows/wave).
// Two chains: in-wave ILP on the serial layer chain + every LDS param read is
// shared by both rows (halves LDS-pipe traffic per row vs R7).
// __launch_bounds__(512,2): VGPR cap 256. History: cap 32 (R4) spilled, cap 64
// (R12) compiler targeted 64 and spilled ~28MB; this body needs ~95 live regs,
// so only the 256-tier cap admits it (lands at 4 waves/SIMD for <=128 VGPR).
__global__ __launch_bounds__(512, 2) void k_main(
    const float* __restrict__ z_in, float* __restrict__ z_out,
    const float* __restrict__ pw, const float* __restrict__ pb,
    const float* __restrict__ ps, const float* __restrict__ rz0,
    const float* __restrict__ ra, const float* __restrict__ rb,
    __half* __restrict__ h_ws, float* __restrict__ pbw)
{
    __shared__ float swp[8 * DDIM];
    __shared__ float ssp[8 * DDIM];
    __shared__ float sz0[8 * DDIM];
    __shared__ float sscal[32];   // [0..7]=b, [8..15]=wdots, [16..23]=a, [24..31]=beta

    const int wave = threadIdx.x >> 6;
    const int lane = threadIdx.x & 63;

    // --- prologue: wave p computes layer-pair p's corrected params (sync-free) ---
    {
        const int p = wave;
        const int ip = 2 * p, ir = 2 * p + 1;
        float4 wv  = ((const float4*)(pw  + ip * DDIM))[lane];
        float4 sv  = ((const float4*)(ps  + ip * DDIM))[lane];
        float4 z0v = ((const float4*)(rz0 + ir * DDIM))[lane];
        float m  = wv.x * sv.x + wv.y * sv.y + wv.z * sv.z + wv.w * sv.w;
        float n2 = wv.x * wv.x + wv.y * wv.y + wv.z * wv.z + wv.w * wv.w;
#pragma unroll
        for (int o = 1; o < 64; o <<= 1) {
            m  += __shfl_xor(m,  o, 64);
            n2 += __shfl_xor(n2, o, 64);
        }
        if (m < -1.0f) {                      // wave-uniform branch
            float comp = -1.0f + log1pf(expf(m)) - m;
            float f = comp * __builtin_amdgcn_rsqf(n2);
            sv.x += f * wv.x; sv.y += f * wv.y; sv.z += f * wv.z; sv.w += f * wv.w;
        }
        float wd = wv.x * sv.x + wv.y * sv.y + wv.z * sv.z + wv.w * sv.w;
#pragma unroll
        for (int o = 1; o < 64; o <<= 1) wd += __shfl_xor(wd, o, 64);
        // permuted store: element d=lane*4+c -> ((lane&3)<<6)|((lane>>2)<<2)|c
        const int nd = ((lane & 3) << 6) | ((lane >> 2) << 2);
        *((float4*)(swp + p * DDIM + nd)) = wv;
        *((float4*)(ssp + p * DDIM + nd)) = sv;
        *((float4*)(sz0 + p * DDIM + nd)) = z0v;
        if (lane == 0) {
            sscal[p]      = pb[ip];
            sscal[8 + p]  = wd;
            float a = ra[ir], bt = rb[ir];
            if (bt < -a) bt = -a + log1pf(expf(bt));
            sscal[16 + p] = a;
            sscal[24 + p] = bt;
        }
    }
    __syncthreads();

    float pbv[8], wds[8], av[8], bv[8];
#pragma unroll
    for (int p = 0; p < 8; ++p) {
        pbv[p] = uni(sscal[p]);
        wds[p] = uni(sscal[8 + p]);
        av[p]  = uni(sscal[16 + p]);
        bv[p]  = uni(sscal[24 + p]);
    }

    const int g = lane >> 4;      // row-group-in-wave 0..3
    const int j = lane & 15;      // chunk index in row
    const int rowA = blockIdx.x * 64 + wave * 8 + g;
    const int rowB = rowA + 4;

    float4 zvA[4], zvB[4];
    {
        const float4* zpA = (const float4*)(z_in + (size_t)rowA * DDIM + j * 16);
        const float4* zpB = (const float4*)(z_in + (size_t)rowB * DDIM + j * 16);
#pragma unroll
        for (int k = 0; k < 4; ++k) { zvA[k] = zpA[k]; zvB[k] = zpB[k]; }
    }

    float acc_ss[8];            // per-lane sum of rowA+rowB r^2 (valid on j==0)
    float acc_pl = 0.0f;
    unsigned hwA[4], hwB[4];

#pragma unroll
    for (int i = 0; i < 16; ++i) {
        if ((i & 1) == 0) {               // planar
            const int p = i >> 1;
            const float4* wb = ((const float4*)swp) + p * 64 + j;
            float4 w0 = wb[0], w1 = wb[16], w2 = wb[32], w3 = wb[48];
            float tA0 = zvA[0].x * w0.x + zvA[0].y * w0.y + zvA[0].z * w0.z + zvA[0].w * w0.w;
            float tB0 = zvB[0].x * w0.x + zvB[0].y * w0.y + zvB[0].z * w0.z + zvB[0].w * w0.w;
            float tA1 = zvA[1].x * w1.x + zvA[1].y * w1.y + zvA[1].z * w1.z + zvA[1].w * w1.w;
            float tB1 = zvB[1].x * w1.x + zvB[1].y * w1.y + zvB[1].z * w1.z + zvB[1].w * w1.w;
            float tA2 = zvA[2].x * w2.x + zvA[2].y * w2.y + zvA[2].z * w2.z + zvA[2].w * w2.w;
            float tB2 = zvB[2].x * w2.x + zvB[2].y * w2.y + zvB[2].z * w2.z + zvB[2].w * w2.w;
            float tA3 = zvA[3].x * w3.x + zvA[3].y * w3.y + zvA[3].z * w3.z + zvA[3].w * w3.w;
            float tB3 = zvB[3].x * w3.x + zvB[3].y * w3.y + zvB[3].z * w3.z + zvB[3].w * w3.w;
            float tA = (tA0 + tA1) + (tA2 + tA3);
            float tB = (tB0 + tB1) + (tB2 + tB3);
            REDUCE16(tA);
            REDUCE16(tB);
            float xA = tA + pbv[p], xB = tB + pbv[p];
            float eA = __expf(2.0f * xA), eB = __expf(2.0f * xB);
            float actA = 1.0f - 2.0f * __builtin_amdgcn_rcpf(eA + 1.0f);
            float actB = 1.0f - 2.0f * __builtin_amdgcn_rcpf(eB + 1.0f);
            const float4* sb = ((const float4*)ssp) + p * 64 + j;
            float4 s0 = sb[0], s1 = sb[16], s2 = sb[32], s3 = sb[48];
            zvA[0].x += s0.x * actA; zvA[0].y += s0.y * actA; zvA[0].z += s0.z * actA; zvA[0].w += s0.w * actA;
            zvB[0].x += s0.x * actB; zvB[0].y += s0.y * actB; zvB[0].z += s0.z * actB; zvB[0].w += s0.w * actB;
            zvA[1].x += s1.x * actA; zvA[1].y += s1.y * actA; zvA[1].z += s1.z * actA; zvA[1].w += s1.w * actA;
            zvB[1].x += s1.x * actB; zvB[1].y += s1.y * actB; zvB[1].z += s1.z * actB; zvB[1].w += s1.w * actB;
            zvA[2].x += s2.x * actA; zvA[2].y += s2.y * actA; zvA[2].z += s2.z * actA; zvA[2].w += s2.w * actA;
            zvB[2].x += s2.x * actB; zvB[2].y += s2.y * actB; zvB[2].z += s2.z * actB; zvB[2].w += s2.w * actB;
            zvA[3].x += s3.x * actA; zvA[3].y += s3.y * actA; zvA[3].z += s3.z * actA; zvA[3].w += s3.w * actA;
            zvB[3].x += s3.x * actB; zvB[3].y += s3.y * actB; zvB[3].z += s3.z * actB; zvB[3].w += s3.w * actB;
            float detA = 1.0f + (1.0f - actA * actA) * wds[p];
            float detB = 1.0f + (1.0f - actB * actB) * wds[p];
            acc_pl += (j == 0) ? (__logf(fabsf(detA) + EPSF) + __logf(fabsf(detB) + EPSF)) : 0.0f;
        } else {                           // radial
            const int r = i >> 1;
            const float4* zb = ((const float4*)sz0) + r * 64 + j;
            float4 z0 = zb[0], z1 = zb[16], z2 = zb[32], z3 = zb[48];
            float4 rdA[4], rdB[4];
            rdA[0].x = zvA[0].x - z0.x; rdA[0].y = zvA[0].y - z0.y; rdA[0].z = zvA[0].z - z0.z; rdA[0].w = zvA[0].w - z0.w;
            rdB[0].x = zvB[0].x - z0.x; rdB[0].y = zvB[0].y - z0.y; rdB[0].z = zvB[0].z - z0.z; rdB[0].w = zvB[0].w - z0.w;
            rdA[1].x = zvA[1].x - z1.x; rdA[1].y = zvA[1].y - z1.y; rdA[1].z = zvA[1].z - z1.z; rdA[1].w = zvA[1].w - z1.w;
            rdB[1].x = zvB[1].x - z1.x; rdB[1].y = zvB[1].y - z1.y; rdB[1].z = zvB[1].z - z1.z; rdB[1].w = zvB[1].w - z1.w;
            rdA[2].x = zvA[2].x - z2.x; rdA[2].y = zvA[2].y - z2.y; rdA[2].z = zvA[2].z - z2.z; rdA[2].w = zvA[2].w - z2.w;
            rdB[2].x = zvB[2].x - z2.x; rdB[2].y = zvB[2].y - z2.y; rdB[2].z = zvB[2].z - z2.z; rdB[2].w = zvB[2].w - z2.w;
            rdA[3].x = zvA[3].x - z3.x; rdA[3].y = zvA[3].y - z3.y; rdA[3].z = zvA[3].z - z3.z; rdA[3].w = zvA[3].w - z3.w;
            rdB[3].x = zvB[3].x - z3.x; rdB[3].y = zvB[3].y - z3.y; rdB[3].z = zvB[3].z - z3.z; rdB[3].w = zvB[3].w - z3.w;
            float tA0 = rdA[0].x * rdA[0].x + rdA[0].y * rdA[0].y + rdA[0].z * rdA[0].z + rdA[0].w * rdA[0].w;
            float tB0 = rdB[0].x * rdB[0].x + rdB[0].y * rdB[0].y + rdB[0].z * rdB[0].z + rdB[0].w * rdB[0].w;
            float tA1 = rdA[1].x * rdA[1].x + rdA[1].y * rdA[1].y + rdA[1].z * rdA[1].z + rdA[1].w * rdA[1].w;
            float tB1 = rdB[1].x * rdB[1].x + rdB[1].y * rdB[1].y + rdB[1].z * rdB[1].z + rdB[1].w * rdB[1].w;
            float tA2 = rdA[2].x * rdA[2].x + rdA[2].y * rdA[2].y + rdA[2].z * rdA[2].z + rdA[2].w * rdA[2].w;
            float tB2 = rdB[2].x * rdB[2].x + rdB[2].y * rdB[2].y + rdB[2].z * rdB[2].z + rdB[2].w * rdB[2].w;
            float tA3 = rdA[3].x * rdA[3].x + rdA[3].y * rdA[3].y + rdA[3].z * rdA[3].z + rdA[3].w * rdA[3].w;
            float tB3 = rdB[3].x * rdB[3].x + rdB[3].y * rdB[3].y + rdB[3].z * rdB[3].z + rdB[3].w * rdB[3].w;
            float tA = (tA0 + tA1) + (tA2 + tA3);
            float tB = (tB0 + tB1) + (tB2 + tB3);
            REDUCE16(tA);
            REDUCE16(tB);
            float rrA = __builtin_amdgcn_sqrtf(tA), rrB = __builtin_amdgcn_sqrtf(tB);
            float hA = __builtin_amdgcn_rcpf(av[r] + rrA);
            float hB = __builtin_amdgcn_rcpf(av[r] + rrB);
            float bhA = bv[r] * hA, bhB = bv[r] * hB;
#pragma unroll
            for (int k = 0; k < 4; ++k) {
                zvA[k].x += bhA * rdA[k].x; zvA[k].y += bhA * rdA[k].y;
                zvA[k].z += bhA * rdA[k].z; zvA[k].w += bhA * rdA[k].w;
                zvB[k].x += bhB * rdB[k].x; zvB[k].y += bhB * rdB[k].y;
                zvB[k].z += bhB * rdB[k].z; zvB[k].w += bhB * rdB[k].w;
            }
            acc_ss[r] = (j == 0) ? (tA + tB) : 0.0f;
            unsigned huA = (unsigned)__half_as_ushort(__float2half(hA));
            unsigned huB = (unsigned)__half_as_ushort(__float2half(hB));
            if ((r & 1) == 0) { hwA[r >> 1] = huA;        hwB[r >> 1] = huB; }
            else              { hwA[r >> 1] |= huA << 16; hwB[r >> 1] |= huB << 16; }
        }
    }

    {
        float4* opA = (float4*)(z_out + (size_t)rowA * DDIM + j * 16);
        float4* opB = (float4*)(z_out + (size_t)rowB * DDIM + j * 16);
#pragma unroll
        for (int k = 0; k < 4; ++k) { opA[k] = zvA[k]; opB[k] = zvB[k]; }
        if (j == 0) {
            ((uint4*)h_ws)[rowA] = make_uint4(hwA[0], hwA[1], hwA[2], hwA[3]);
            ((uint4*)h_ws)[rowB] = make_uint4(hwB[0], hwB[1], hwB[2], hwB[3]);
        }
    }

    // per-wave partials: combine the 4 row-groups, one store per wave
    const int waveId = blockIdx.x * 8 + wave;
#pragma unroll
    for (int q = 0; q < 9; ++q) {
        float v = (q < 8) ? acc_ss[q] : acc_pl;
        v += __shfl_xor(v, 16, 64);
        v += __shfl_xor(v, 32, 64);
        if (lane == 0) pbw[waveId * 9 + q] = v;
    }
}

// ---------------- k2: reduce wave partials -> R[8], planar loss (9 blocks) ----------------
__global__ __launch_bounds__(1024) void k_stats(
    const float* __restrict__ pbw, double* __restrict__ Rv, double* __restrict__ PL)
{
    __shared__ double sd[1024];
    const int q = blockIdx.x;
    const int t = threadIdx.x;
    double v = 0.0;
    for (int i = t; i < NWAVES; i += 1024) v += (double)pbw[i * 9 + q];
    sd[t] = v;
    __syncthreads();
#pragma unroll
    for (int off = 512; off > 0; off >>= 1) {
        if (t < off) sd[t] += sd[t + off];
        __syncthreads();
    }
    if (t == 0) {
        if (q < 8) Rv[q] = sqrt(sd[0]);
        else       PL[0] = sd[0];
    }
}

// ---------------- k3: radial loss (needs global R) ----------------
__global__ __launch_bounds__(256) void k_rloss(
    const __half* __restrict__ h_ws, const float* __restrict__ ra,
    const float* __restrict__ rb, const double* __restrict__ Rv,
    double* __restrict__ pb_rl)
{
    __shared__ double sd[256];
    __shared__ float sbeta[8], sR[8];
    if (threadIdx.x < 8) {
        int r = threadIdx.x;
        float a = ra[2 * r + 1], bt = rb[2 * r + 1];
        if (bt < -a) bt = -a + log1pf(expf(bt));
        sbeta[r] = bt;
        sR[r] = (float)Rv[r];
    }
    __syncthreads();
    const int row = blockIdx.x * 256 + threadIdx.x;
    uint4 hp = ((const uint4*)h_ws)[row];
    unsigned hw[4] = {hp.x, hp.y, hp.z, hp.w};
    double ls = 0.0;
#pragma unroll
    for (int r = 0; r < 8; ++r) {
        unsigned hu = (hw[r >> 1] >> ((r & 1) * 16)) & 0xFFFFu;
        float h = __half2float(__ushort_as_half((unsigned short)hu));
        float beta = sbeta[r];
        float bh = beta * h;
        float t1 = 1.0f + bh;
        float diag = exp2f(255.0f * __log2f(t1));      // t1^255, t1>0
        float det = diag * (t1 - beta * h * h * sR[r]);
        ls += (double)__logf(fabsf(det) + EPSF);
    }
    sd[threadIdx.x] = ls;
    __syncthreads();
#pragma unroll
    for (int off = 128; off > 0; off >>= 1) {
        if (threadIdx.x < off) sd[threadIdx.x] += sd[threadIdx.x + off];
        __syncthreads();
    }
    if (threadIdx.x == 0) pb_rl[blockIdx.x] = sd[0];
}

// ---------------- k4: final combine ----------------
__global__ __launch_bounds__(256) void k_final(
    const double* __restrict__ pb_rl, const double* __restrict__ PL,
    float* __restrict__ out_loss)
{
    __shared__ double sd[256];
    int t = threadIdx.x;
    double v = 0.0;
    for (int jj = t; jj < NB3; jj += 256) v += pb_rl[jj];
    sd[t] = v;
    __syncthreads();
#pragma unroll
    for (int off = 128; off > 0; off >>= 1) {
        if (t < off) sd[t] += sd[t + off];
        __syncthreads();
    }
    if (t == 0) out_loss[0] = (float)((sd[0] + PL[0]) / (double)B_ROWS);
}

extern "C" void kernel_launch(void* const* d_in, const int* in_sizes, int n_in,
                              void* d_out, int out_size, void* d_ws, size_t ws_size,
                              hipStream_t stream) {
    const float* z   = (const float*)d_in[0];
    const float* pw  = (const float*)d_in[1];
    const float* pb  = (const float*)d_in[2];
    const float* ps  = (const float*)d_in[3];
    const float* rz0 = (const float*)d_in[4];
    const float* ra  = (const float*)d_in[5];
    const float* rb  = (const float*)d_in[6];
    float* out = (float*)d_out;

    char* ws = (char*)d_ws;
    float*  pbw   = (float*)(ws + PBW_OFF);
    double* Rv    = (double*)(ws + RV_OFF);
    double* PL    = (double*)(ws + PL_OFF);
    double* pb_rl = (double*)(ws + PBRL_OFF);
    __half* h_ws  = (__half*)(ws + HW_OFF);

    k_main<<<NB1, 512, 0, stream>>>(z, out, pw, pb, ps, rz0, ra, rb, h_ws, pbw);
    k_stats<<<9, 1024, 0, stream>>>(pbw, Rv, PL);
    k_rloss<<<NB3, 256, 0, stream>>>(h_ws, ra, rb, Rv, pb_rl);
    k_final<<<1, 256, 0, stream>>>(pb_rl, PL, out + (size_t)B_ROWS * DDIM);
}

// Round 14
// 90.805 us; speedup vs baseline: 1.1032x; 1.1032x over previous
//
#include <hip/hip_runtime.h>
#include <hip/hip_fp16.h>
#include <math.h>

#define B_ROWS 131072
#define DDIM 256
#define EPSF 1e-7f
#define NB1 4096            // k_main blocks; 512 thr, 8 waves, 32 rows/block
#define NWAVES (NB1 * 8)    // 32768 per-wave partial slots
#define NB3 512             // k_rloss blocks; NB3*256 == B_ROWS

// ---------- ws layout (bytes) ----------
#define PBW_OFF  0          // float[NWAVES][9] = 1179648
#define RV_OFF   1179648    // double[8]
#define PL_OFF   1179712    // double[1]
#define PBRL_OFF 1179776    // double[NB3] = 4096
#define HW_OFF   1183872    // __half[B_ROWS][8] = 2 MB (end ~3.28 MB)

// BEST-KNOWN CONFIGURATION (R7: 90.96 us total, k_main ~93 us, 40 VGPR, no spill).
// Journal of falsified alternatives (keep for future readers):
//  - R8/R9/R10: persistent blocks / outer tile loop / 2-tile straight-line all
//    triggered scratch demotion (FETCH 66MB -> 0.1-1.7GB). Any cross-tile
//    register liveness spills.
//  - R11: f16 params in LDS: LDS pipe was NOT binding; cvt overhead + pressure
//    cost more than halved LDS bytes (111 us).
//  - R12/R13: 2 row-chains/lane (ILP): cap 64 spills; cap 256 is clean but
//    halves residency -> 111 us. ILP gain < occupancy loss at every cap tier.

__device__ __forceinline__ float uni(float x) {   // wave-uniform -> SGPR
    return __int_as_float(__builtin_amdgcn_readfirstlane(__float_as_int(x)));
}

// DPP-based add: v += v permuted by ctrl (within 16-lane DPP rows). VALU-only.
#define DPP_ADD(v, ctrl)                                                        \
    (v) += __int_as_float(__builtin_amdgcn_update_dpp(                          \
               0, __float_as_int(v), (ctrl), 0xF, 0xF, true))

// 16-lane all-reduce sum: xor1, xor2 via quad_perm; then row_ror:4, row_ror:8.
#define REDUCE16(v)                                                             \
    do {                                                                        \
        DPP_ADD(v, 0xB1);   /* quad_perm [1,0,3,2]  */                          \
        DPP_ADD(v, 0x4E);   /* quad_perm [2,3,0,1]  */                          \
        DPP_ADD(v, 0x124);  /* row_ror:4            */                          \
        DPP_ADD(v, 0x128);  /* row_ror:8            */                          \
    } while (0)

// ---------------- k1: fused params + main chain ----------------
// 512 threads = 8 waves; wave handles 4 rows (16 lanes/row, 16 elems/lane).
__global__ __launch_bounds__(512, 6) void k_main(
    const float* __restrict__ z_in, float* __restrict__ z_out,
    const float* __restrict__ pw, const float* __restrict__ pb,
    const float* __restrict__ ps, const float* __restrict__ rz0,
    const float* __restrict__ ra, const float* __restrict__ rb,
    __half* __restrict__ h_ws, float* __restrict__ pbw)
{
    __shared__ float swp[8 * DDIM];
    __shared__ float ssp[8 * DDIM];
    __shared__ float sz0[8 * DDIM];
    __shared__ float sscal[32];   // [0..7]=b, [8..15]=wdots, [16..23]=a, [24..31]=beta

    const int wave = threadIdx.x >> 6;
    const int lane = threadIdx.x & 63;

    // --- prologue: wave p computes layer-pair p's corrected params (sync-free) ---
    {
        const int p = wave;
        const int ip = 2 * p, ir = 2 * p + 1;
        float4 wv  = ((const float4*)(pw  + ip * DDIM))[lane];
        float4 sv  = ((const float4*)(ps  + ip * DDIM))[lane];
        float4 z0v = ((const float4*)(rz0 + ir * DDIM))[lane];
        float m  = wv.x * sv.x + wv.y * sv.y + wv.z * sv.z + wv.w * sv.w;
        float n2 = wv.x * wv.x + wv.y * wv.y + wv.z * wv.z + wv.w * wv.w;
#pragma unroll
        for (int o = 1; o < 64; o <<= 1) {
            m  += __shfl_xor(m,  o, 64);
            n2 += __shfl_xor(n2, o, 64);
        }
        if (m < -1.0f) {                      // wave-uniform branch
            float comp = -1.0f + log1pf(expf(m)) - m;
            float f = comp * __builtin_amdgcn_rsqf(n2);
            sv.x += f * wv.x; sv.y += f * wv.y; sv.z += f * wv.z; sv.w += f * wv.w;
        }
        float wd = wv.x * sv.x + wv.y * sv.y + wv.z * sv.z + wv.w * sv.w;
#pragma unroll
        for (int o = 1; o < 64; o <<= 1) wd += __shfl_xor(wd, o, 64);
        // permuted store: element d=lane*4+c -> ((lane&3)<<6)|((lane>>2)<<2)|c
        const int nd = ((lane & 3) << 6) | ((lane >> 2) << 2);
        *((float4*)(swp + p * DDIM + nd)) = wv;
        *((float4*)(ssp + p * DDIM + nd)) = sv;
        *((float4*)(sz0 + p * DDIM + nd)) = z0v;
        if (lane == 0) {
            sscal[p]      = pb[ip];
            sscal[8 + p]  = wd;
            float a = ra[ir], bt = rb[ir];
            if (bt < -a) bt = -a + log1pf(expf(bt));
            sscal[16 + p] = a;
            sscal[24 + p] = bt;
        }
    }
    __syncthreads();

    float pbv[8], wds[8], av[8], bv[8];
#pragma unroll
    for (int p = 0; p < 8; ++p) {
        pbv[p] = uni(sscal[p]);
        wds[p] = uni(sscal[8 + p]);
        av[p]  = uni(sscal[16 + p]);
        bv[p]  = uni(sscal[24 + p]);
    }

    const int g = lane >> 4;      // row-in-wave 0..3
    const int j = lane & 15;      // chunk index in row
    const int row = blockIdx.x * 32 + wave * 4 + g;

    float4 zv[4];
    {
        const float4* zp = (const float4*)(z_in + (size_t)row * DDIM + j * 16);
#pragma unroll
        for (int k = 0; k < 4; ++k) zv[k] = zp[k];
    }

    float r2s[8];
    float pls = 0.0f;
    unsigned hw32[4];

#pragma unroll
    for (int i = 0; i < 16; ++i) {
        if ((i & 1) == 0) {               // planar
            const int p = i >> 1;
            const float4* wb = ((const float4*)swp) + p * 64 + j;
            // 4 independent partial dot-products (ILP), pairwise combine
            float t0, t1, t2, t3;
            {
                float4 w0 = wb[0], w1 = wb[16], w2 = wb[32], w3 = wb[48];
                t0 = zv[0].x * w0.x + zv[0].y * w0.y + zv[0].z * w0.z + zv[0].w * w0.w;
                t1 = zv[1].x * w1.x + zv[1].y * w1.y + zv[1].z * w1.z + zv[1].w * w1.w;
                t2 = zv[2].x * w2.x + zv[2].y * w2.y + zv[2].z * w2.z + zv[2].w * w2.w;
                t3 = zv[3].x * w3.x + zv[3].y * w3.y + zv[3].z * w3.z + zv[3].w * w3.w;
            }
            float t = (t0 + t1) + (t2 + t3);
            REDUCE16(t);
            float x = t + pbv[p];
            float e = __expf(2.0f * x);
            float act = 1.0f - 2.0f * __builtin_amdgcn_rcpf(e + 1.0f);  // tanh(x)
            const float4* sb = ((const float4*)ssp) + p * 64 + j;
#pragma unroll
            for (int k = 0; k < 4; ++k) {
                float4 sv = sb[k * 16];
                zv[k].x += sv.x * act; zv[k].y += sv.y * act;
                zv[k].z += sv.z * act; zv[k].w += sv.w * act;
            }
            float det = 1.0f + (1.0f - act * act) * wds[p];
            pls += __logf(fabsf(det) + EPSF);
        } else {                           // radial
            const int r = i >> 1;
            const float4* zb = ((const float4*)sz0) + r * 64 + j;
            float4 rd[4];
            float t0, t1, t2, t3;
            {
                float4 z0 = zb[0], z1 = zb[16], z2 = zb[32], z3 = zb[48];
                rd[0].x = zv[0].x - z0.x; rd[0].y = zv[0].y - z0.y;
                rd[0].z = zv[0].z - z0.z; rd[0].w = zv[0].w - z0.w;
                rd[1].x = zv[1].x - z1.x; rd[1].y = zv[1].y - z1.y;
                rd[1].z = zv[1].z - z1.z; rd[1].w = zv[1].w - z1.w;
                rd[2].x = zv[2].x - z2.x; rd[2].y = zv[2].y - z2.y;
                rd[2].z = zv[2].z - z2.z; rd[2].w = zv[2].w - z2.w;
                rd[3].x = zv[3].x - z3.x; rd[3].y = zv[3].y - z3.y;
                rd[3].z = zv[3].z - z3.z; rd[3].w = zv[3].w - z3.w;
                t0 = rd[0].x * rd[0].x + rd[0].y * rd[0].y + rd[0].z * rd[0].z + rd[0].w * rd[0].w;
                t1 = rd[1].x * rd[1].x + rd[1].y * rd[1].y + rd[1].z * rd[1].z + rd[1].w * rd[1].w;
                t2 = rd[2].x * rd[2].x + rd[2].y * rd[2].y + rd[2].z * rd[2].z + rd[2].w * rd[2].w;
                t3 = rd[3].x * rd[3].x + rd[3].y * rd[3].y + rd[3].z * rd[3].z + rd[3].w * rd[3].w;
            }
            float t = (t0 + t1) + (t2 + t3);
            REDUCE16(t);
            float rr = __builtin_amdgcn_sqrtf(t);
            float h = __builtin_amdgcn_rcpf(av[r] + rr);
            float bh = bv[r] * h;
#pragma unroll
            for (int k = 0; k < 4; ++k) {
                zv[k].x += bh * rd[k].x; zv[k].y += bh * rd[k].y;
                zv[k].z += bh * rd[k].z; zv[k].w += bh * rd[k].w;
            }
            r2s[r] = t;
            unsigned hu = (unsigned)__half_as_ushort(__float2half(h));
            if ((r & 1) == 0) hw32[r >> 1] = hu;
            else              hw32[r >> 1] |= hu << 16;
        }
    }

    {
        float4* op = (float4*)(z_out + (size_t)row * DDIM + j * 16);
#pragma unroll
        for (int k = 0; k < 4; ++k) op[k] = zv[k];
        if (j == 0)
            ((uint4*)h_ws)[row] = make_uint4(hw32[0], hw32[1], hw32[2], hw32[3]);
    }

    // per-wave partials: values are row-uniform; combine the 4 row-groups
    const int waveId = blockIdx.x * 8 + wave;
#pragma unroll
    for (int q = 0; q < 9; ++q) {
        float v = (q < 8) ? r2s[q] : pls;
        if (j != 0) v = 0.0f;
        v += __shfl_xor(v, 16, 64);
        v += __shfl_xor(v, 32, 64);
        if (lane == 0) pbw[waveId * 9 + q] = v;
    }
}

// ---------------- k2: reduce wave partials -> R[8], planar loss (9 blocks) ----------------
__global__ __launch_bounds__(1024) void k_stats(
    const float* __restrict__ pbw, double* __restrict__ Rv, double* __restrict__ PL)
{
    __shared__ double sd[1024];
    const int q = blockIdx.x;
    const int t = threadIdx.x;
    double v = 0.0;
    for (int i = t; i < NWAVES; i += 1024) v += (double)pbw[i * 9 + q];
    sd[t] = v;
    __syncthreads();
#pragma unroll
    for (int off = 512; off > 0; off >>= 1) {
        if (t < off) sd[t] += sd[t + off];
        __syncthreads();
    }
    if (t == 0) {
        if (q < 8) Rv[q] = sqrt(sd[0]);
        else       PL[0] = sd[0];
    }
}

// ---------------- k3: radial loss (needs global R) ----------------
__global__ __launch_bounds__(256) void k_rloss(
    const __half* __restrict__ h_ws, const float* __restrict__ ra,
    const float* __restrict__ rb, const double* __restrict__ Rv,
    double* __restrict__ pb_rl)
{
    __shared__ double sd[256];
    __shared__ float sbeta[8], sR[8];
    if (threadIdx.x < 8) {
        int r = threadIdx.x;
        float a = ra[2 * r + 1], bt = rb[2 * r + 1];
        if (bt < -a) bt = -a + log1pf(expf(bt));
        sbeta[r] = bt;
        sR[r] = (float)Rv[r];
    }
    __syncthreads();
    const int row = blockIdx.x * 256 + threadIdx.x;
    uint4 hp = ((const uint4*)h_ws)[row];
    unsigned hw[4] = {hp.x, hp.y, hp.z, hp.w};
    double ls = 0.0;
#pragma unroll
    for (int r = 0; r < 8; ++r) {
        unsigned hu = (hw[r >> 1] >> ((r & 1) * 16)) & 0xFFFFu;
        float h = __half2float(__ushort_as_half((unsigned short)hu));
        float beta = sbeta[r];
        float bh = beta * h;
        float t1 = 1.0f + bh;
        float diag = exp2f(255.0f * __log2f(t1));      // t1^255, t1>0
        float det = diag * (t1 - beta * h * h * sR[r]);
        ls += (double)__logf(fabsf(det) + EPSF);
    }
    sd[threadIdx.x] = ls;
    __syncthreads();
#pragma unroll
    for (int off = 128; off > 0; off >>= 1) {
        if (threadIdx.x < off) sd[threadIdx.x] += sd[threadIdx.x + off];
        __syncthreads();
    }
    if (threadIdx.x == 0) pb_rl[blockIdx.x] = sd[0];
}

// ---------------- k4: final combine ----------------
__global__ __launch_bounds__(256) void k_final(
    const double* __restrict__ pb_rl, const double* __restrict__ PL,
    float* __restrict__ out_loss)
{
    __shared__ double sd[256];
    int t = threadIdx.x;
    double v = 0.0;
    for (int jj = t; jj < NB3; jj += 256) v += pb_rl[jj];
    sd[t] = v;
    __syncthreads();
#pragma unroll
    for (int off = 128; off > 0; off >>= 1) {
        if (t < off) sd[t] += sd[t + off];
        __syncthreads();
    }
    if (t == 0) out_loss[0] = (float)((sd[0] + PL[0]) / (double)B_ROWS);
}

extern "C" void kernel_launch(void* const* d_in, const int* in_sizes, int n_in,
                              void* d_out, int out_size, void* d_ws, size_t ws_size,
                              hipStream_t stream) {
    const float* z   = (const float*)d_in[0];
    const float* pw  = (const float*)d_in[1];
    const float* pb  = (const float*)d_in[2];
    const float* ps  = (const float*)d_in[3];
    const float* rz0 = (const float*)d_in[4];
    const float* ra  = (const float*)d_in[5];
    const float* rb  = (const float*)d_in[6];
    float* out = (float*)d_out;

    char* ws = (char*)d_ws;
    float*  pbw   = (float*)(ws + PBW_OFF);
    double* Rv    = (double*)(ws + RV_OFF);
    double* PL    = (double*)(ws + PL_OFF);
    double* pb_rl = (double*)(ws + PBRL_OFF);
    __half* h_ws  = (__half*)(ws + HW_OFF);

    k_main<<<NB1, 512, 0, stream>>>(z, out, pw, pb, ps, rz0, ra, rb, h_ws, pbw);
    k_stats<<<9, 1024, 0, stream>>>(pbw, Rv, PL);
    k_rloss<<<NB3, 256, 0, stream>>>(h_ws, ra, rb, Rv, pb_rl);
    k_final<<<1, 256, 0, stream>>>(pb_rl, PL, out + (size_t)B_ROWS * DDIM);
}